// Round 4
// baseline (1567.211 us; speedup 1.0000x reference)
//
#include <hip/hip_runtime.h>

// RINN controller: B=131072, n_k=64, n_w=128, n_y=16, n_u=16, N_PLANT=16
// xi row: [ y(16) | x_k(64) ] (80 floats)
//
// R3 strategy: 4 threads/element (quad), rows interleaved i=4m+t; each thread
// handles 2 elements (b, b+B/2) packed into v2f -> v_pk_fma_f32.
// Triangular scatter sweep j=127..0; w_j broadcast within quad via DPP
// quad_perm. Matrices permuted in ws so per-thread coeffs are contiguous
// float4 loads. Boundary masking is free: Dvw strictly-upper zeros.

#define NW 128
#define NK 64
#define NY 16
#define NU 16
#define NXI 80

// ws layout (floats)
#define E_OFF    0        // E_perm[k][t][m]   = E[k][4m+t],    80*128 = 10240
#define F_OFF    10240    // F_perm[k][t][q]   = F[k][4t+q],    80*16  = 1280
#define DVWT_OFF 11520    // V_perm[j][t][m]   = Dvw[4m+t][j], 128*128 = 16384
#define DUWT_OFF 27904    // U_perm[j][t][q]   = Duw[4t+q][j], 128*16  = 2048
#define WS_FLOATS 29952

typedef float v2f __attribute__((ext_vector_type(2)));

__global__ void prep_kernel(const float* __restrict__ Cv,
                            const float* __restrict__ Dvw,
                            const float* __restrict__ Dvy,
                            const float* __restrict__ Cu,
                            const float* __restrict__ Duw,
                            const float* __restrict__ Duy,
                            float* __restrict__ ws) {
    int idx = blockIdx.x * blockDim.x + threadIdx.x;
    if (idx >= WS_FLOATS) return;
    float v;
    if (idx < F_OFF) {                       // E_perm: k*128 + t*32 + m
        int k = idx >> 7, r7 = idx & 127;
        int t = r7 >> 5, m = r7 & 31;
        int i = 4 * m + t;
        v = (k < NY) ? Dvy[i * NY + k] : Cv[i * NK + (k - NY)];
    } else if (idx < DVWT_OFF) {             // F_perm: k*16 + t*4 + q
        int tt = idx - F_OFF;
        int k = tt >> 4, r = tt & 15;
        int ru = 4 * (r >> 2) + (r & 3);
        v = (k < NY) ? Duy[ru * NY + k] : Cu[ru * NK + (k - NY)];
    } else if (idx < DUWT_OFF) {             // V_perm: j*128 + t*32 + m
        int tt = idx - DVWT_OFF;
        int j = tt >> 7, r7 = tt & 127;
        int t = r7 >> 5, m = r7 & 31;
        int i = 4 * m + t;
        v = Dvw[i * NW + j];                 // zero for i >= j (strict upper)
    } else {                                 // U_perm: j*16 + t*4 + q
        int tt = idx - DUWT_OFF;
        int j = tt >> 4, r = tt & 15;
        int ru = 4 * (r >> 2) + (r & 3);
        v = Duw[ru * NW + j];
    }
    ws[idx] = v;
}

// Broadcast lane (quadbase + t) -> all 4 lanes of the quad. t is
// compile-time after unrolling, so the switch folds to one v_mov_dpp.
__device__ __forceinline__ float qbcast(float x, int t) {
    int s = __float_as_int(x), r = 0;
    switch (t) {
        case 0: r = __builtin_amdgcn_mov_dpp(s, 0x00, 0xF, 0xF, 0); break;
        case 1: r = __builtin_amdgcn_mov_dpp(s, 0x55, 0xF, 0xF, 0); break;
        case 2: r = __builtin_amdgcn_mov_dpp(s, 0xAA, 0xF, 0xF, 0); break;
        case 3: r = __builtin_amdgcn_mov_dpp(s, 0xFF, 0xF, 0xF, 0); break;
    }
    return __int_as_float(r);
}

__device__ __forceinline__ v2f pkfma(float c, v2f x, v2f acc) {
    v2f cc = {c, c};
    return __builtin_elementwise_fma(cc, x, acc);
}

__global__ __launch_bounds__(256, 4) void rinn_main(const float* __restrict__ xi,
                                                    const float* __restrict__ ws,
                                                    float* __restrict__ out,
                                                    int nhalf) {
    const int tid = blockIdx.x * 256 + threadIdx.x;
    const int gq = tid >> 2;     // quad id = element pair id
    const int t  = tid & 3;      // row-interleave slot: owns rows i = 4m+t
    const int b0 = gq;
    const int b1 = gq + nhalf;

    const float* __restrict__ Ep = ws + E_OFF    + t * 32;
    const float* __restrict__ Fp = ws + F_OFF    + t * 4;
    const float* __restrict__ Vp = ws + DVWT_OFF + t * 32;
    const float* __restrict__ Up = ws + DUWT_OFF + t * 4;

    const float4* __restrict__ xi0 = (const float4*)(xi + (size_t)b0 * NXI);
    const float4* __restrict__ xi1 = (const float4*)(xi + (size_t)b1 * NXI);

    v2f base_v[32];   // base_v[m] = base[row 4m+t] for elements {b0,b1}
    v2f u_v[4];       // u_v[q]    = u[4t+q]        for elements {b0,b1}
#pragma unroll
    for (int m = 0; m < 32; ++m) base_v[m] = (v2f){0.f, 0.f};
#pragma unroll
    for (int q = 0; q < 4; ++q) u_v[q] = (v2f){0.f, 0.f};

    // ---- dense input phase: base += E^T xi, u += F^T xi ----
#pragma unroll
    for (int kk = 0; kk < NXI / 4; ++kk) {
        const float4 x0 = xi0[kk];
        const float4 x1 = xi1[kk];
        const float xs0[4] = {x0.x, x0.y, x0.z, x0.w};
        const float xs1[4] = {x1.x, x1.y, x1.z, x1.w};
#pragma unroll
        for (int c = 0; c < 4; ++c) {
            const int k = kk * 4 + c;
            const v2f xk = {xs0[c], xs1[c]};
#pragma unroll
            for (int l = 0; l < 8; ++l) {
                const float4 e = *(const float4*)(Ep + k * 128 + 4 * l);
                base_v[4 * l + 0] = pkfma(e.x, xk, base_v[4 * l + 0]);
                base_v[4 * l + 1] = pkfma(e.y, xk, base_v[4 * l + 1]);
                base_v[4 * l + 2] = pkfma(e.z, xk, base_v[4 * l + 2]);
                base_v[4 * l + 3] = pkfma(e.w, xk, base_v[4 * l + 3]);
            }
            const float4 f = *(const float4*)(Fp + k * 16);
            u_v[0] = pkfma(f.x, xk, u_v[0]);
            u_v[1] = pkfma(f.y, xk, u_v[1]);
            u_v[2] = pkfma(f.z, xk, u_v[2]);
            u_v[3] = pkfma(f.w, xk, u_v[3]);
        }
    }

    // ---- triangular relu solve, scatter form, j = 127..0 ----
#pragma unroll
    for (int jj = 0; jj < NW; ++jj) {
        const int j  = NW - 1 - jj;
        const int tj = j & 3;     // owner slot of row j
        const int mj = j >> 2;    // owner-local index
        const v2f cand = base_v[mj];
        const v2f w2 = {fmaxf(qbcast(cand.x, tj), 0.f),
                        fmaxf(qbcast(cand.y, tj), 0.f)};

        const float4 du = *(const float4*)(Up + j * 16);
        u_v[0] = pkfma(du.x, w2, u_v[0]);
        u_v[1] = pkfma(du.y, w2, u_v[1]);
        u_v[2] = pkfma(du.z, w2, u_v[2]);
        u_v[3] = pkfma(du.w, w2, u_v[3]);

        const int nL = (j + 15) >> 4;  // float4 loads; tail masked by stored zeros
#pragma unroll
        for (int l = 0; l < nL; ++l) {
            const float4 cc = *(const float4*)(Vp + j * 128 + 4 * l);
            base_v[4 * l + 0] = pkfma(cc.x, w2, base_v[4 * l + 0]);
            base_v[4 * l + 1] = pkfma(cc.y, w2, base_v[4 * l + 1]);
            base_v[4 * l + 2] = pkfma(cc.z, w2, base_v[4 * l + 2]);
            base_v[4 * l + 3] = pkfma(cc.w, w2, base_v[4 * l + 3]);
        }
    }

    // ---- write u: thread t owns u[4t..4t+4) for both elements ----
    const float4 o0 = make_float4(u_v[0].x, u_v[1].x, u_v[2].x, u_v[3].x);
    const float4 o1 = make_float4(u_v[0].y, u_v[1].y, u_v[2].y, u_v[3].y);
    *(float4*)(out + (size_t)b0 * NU + t * 4) = o0;
    *(float4*)(out + (size_t)b1 * NU + t * 4) = o1;
}

extern "C" void kernel_launch(void* const* d_in, const int* in_sizes, int n_in,
                              void* d_out, int out_size, void* d_ws, size_t ws_size,
                              hipStream_t stream) {
    const float* xi  = (const float*)d_in[0];
    const float* Cv  = (const float*)d_in[1];
    const float* Dvw = (const float*)d_in[2];
    const float* Dvy = (const float*)d_in[3];
    const float* Cu  = (const float*)d_in[4];
    const float* Duw = (const float*)d_in[5];
    const float* Duy = (const float*)d_in[6];
    float* out = (float*)d_out;
    float* ws  = (float*)d_ws;

    const int B = in_sizes[0] / NXI;  // 131072
    const int nhalf = B / 2;
    const int threads = nhalf * 4;    // 2 elements per thread

    prep_kernel<<<(WS_FLOATS + 255) / 256, 256, 0, stream>>>(Cv, Dvw, Dvy, Cu, Duw, Duy, ws);
    rinn_main<<<threads / 256, 256, 0, stream>>>(xi, ws, out, nhalf);
}

// Round 5
// 630.963 us; speedup vs baseline: 2.4838x; 2.4838x over previous
//
#include <hip/hip_runtime.h>

// RINN controller: B=131072, n_k=64, n_w=128, n_y=16, n_u=16, N_PLANT=16
// xi row: [ y(16) | x_k(64) ] (80 floats)
//
// R5: R3 structure (4 threads/element quad, rows i=4m+t per slot t, 2 batch
// elements per thread packed in v2f -> v_pk_fma_f32, DPP quad broadcast),
// but ALL loops are template-recursion (ufor) so every array index and DPP
// control is a parse-time constant. R4 failed because the j-dependent inner
// loop bound defeated the unroller -> base_v demoted to scratch (4.9 GB of
// scratch HBM writes, VGPR=64, 1567 us). Rule #20: static indices only.

#define NW 128
#define NK 64
#define NY 16
#define NU 16
#define NXI 80

// ws layout (floats)
#define E_OFF    0        // E_perm[k][t][m]   = E[k][4m+t],    80*128 = 10240
#define F_OFF    10240    // F_perm[k][t][q]   = F[k][4t+q],    80*16  = 1280
#define DVWT_OFF 11520    // V_perm[j][t][m]   = Dvw[4m+t][j], 128*128 = 16384
#define DUWT_OFF 27904    // U_perm[j][t][q]   = Duw[4t+q][j], 128*16  = 2048
#define WS_FLOATS 29952

typedef float v2f __attribute__((ext_vector_type(2)));

template<int I> struct Ic { static constexpr int value = I; };

template<int I, int N, typename F>
__device__ __forceinline__ void ufor(F&& f) {
    if constexpr (I < N) {
        f(Ic<I>{});
        ufor<I + 1, N>(static_cast<F&&>(f));
    }
}

__global__ void prep_kernel(const float* __restrict__ Cv,
                            const float* __restrict__ Dvw,
                            const float* __restrict__ Dvy,
                            const float* __restrict__ Cu,
                            const float* __restrict__ Duw,
                            const float* __restrict__ Duy,
                            float* __restrict__ ws) {
    int idx = blockIdx.x * blockDim.x + threadIdx.x;
    if (idx >= WS_FLOATS) return;
    float v;
    if (idx < F_OFF) {                       // E_perm: k*128 + t*32 + m
        int k = idx >> 7, r7 = idx & 127;
        int t = r7 >> 5, m = r7 & 31;
        int i = 4 * m + t;
        v = (k < NY) ? Dvy[i * NY + k] : Cv[i * NK + (k - NY)];
    } else if (idx < DVWT_OFF) {             // F_perm: k*16 + t*4 + q
        int tt = idx - F_OFF;
        int k = tt >> 4, r = tt & 15;       // r = t*4+q
        v = (k < NY) ? Duy[r * NY + k] : Cu[r * NK + (k - NY)];
    } else if (idx < DUWT_OFF) {             // V_perm: j*128 + t*32 + m
        int tt = idx - DVWT_OFF;
        int j = tt >> 7, r7 = tt & 127;
        int t = r7 >> 5, m = r7 & 31;
        int i = 4 * m + t;
        v = Dvw[i * NW + j];                 // zero for i >= j (strict upper)
    } else {                                 // U_perm: j*16 + t*4 + q
        int tt = idx - DUWT_OFF;
        int j = tt >> 4, r = tt & 15;       // r = t*4+q = u index
        v = Duw[r * NW + j];
    }
    ws[idx] = v;
}

// Broadcast quad lane T (0..3) to all 4 lanes; T is a template constant so
// the dpp_ctrl immediate is compile-time.
template<int T>
__device__ __forceinline__ float qbcast(float x) {
    constexpr int ctrl = T * 0x55;  // [T,T,T,T] quad_perm
    return __int_as_float(
        __builtin_amdgcn_mov_dpp(__float_as_int(x), ctrl, 0xF, 0xF, false));
}

__device__ __forceinline__ v2f pkfma(float c, v2f x, v2f acc) {
    v2f cc = {c, c};
    return __builtin_elementwise_fma(cc, x, acc);
}

__global__ __launch_bounds__(256, 4) void rinn_main(const float* __restrict__ xi,
                                                    const float* __restrict__ ws,
                                                    float* __restrict__ out,
                                                    int nhalf) {
    const int tid = blockIdx.x * 256 + threadIdx.x;
    const int gq = tid >> 2;     // element-pair id
    const int t  = tid & 3;      // row slot: owns rows i = 4m+t
    const int b0 = gq;
    const int b1 = gq + nhalf;

    const float* __restrict__ Ep = ws + E_OFF    + t * 32;
    const float* __restrict__ Fp = ws + F_OFF    + t * 4;
    const float* __restrict__ Vp = ws + DVWT_OFF + t * 32;
    const float* __restrict__ Up = ws + DUWT_OFF + t * 4;

    const float4* __restrict__ xi0 = (const float4*)(xi + (size_t)b0 * NXI);
    const float4* __restrict__ xi1 = (const float4*)(xi + (size_t)b1 * NXI);

    v2f base_v[32];   // base_v[m] = base[row 4m+t] for elements {b0,b1}
    v2f u_v[4];       // u_v[q]    = u[4t+q]        for elements {b0,b1}
    ufor<0, 32>([&](auto M) { base_v[M.value] = (v2f){0.f, 0.f}; });
    ufor<0, 4>([&](auto Q) { u_v[Q.value] = (v2f){0.f, 0.f}; });

    // ---- dense input phase: base += E^T xi, u += F^T xi ----
    ufor<0, NXI / 4>([&](auto KK) {
        constexpr int kk = KK.value;
        const float4 x0 = xi0[kk];
        const float4 x1 = xi1[kk];
        ufor<0, 4>([&](auto C) {
            constexpr int c = C.value;
            constexpr int k = kk * 4 + c;
            const float a0 = (c == 0) ? x0.x : (c == 1) ? x0.y : (c == 2) ? x0.z : x0.w;
            const float a1 = (c == 0) ? x1.x : (c == 1) ? x1.y : (c == 2) ? x1.z : x1.w;
            const v2f xk = {a0, a1};
            ufor<0, 8>([&](auto L) {
                constexpr int l = L.value;
                const float4 e = *(const float4*)(Ep + k * 128 + 4 * l);
                base_v[4 * l + 0] = pkfma(e.x, xk, base_v[4 * l + 0]);
                base_v[4 * l + 1] = pkfma(e.y, xk, base_v[4 * l + 1]);
                base_v[4 * l + 2] = pkfma(e.z, xk, base_v[4 * l + 2]);
                base_v[4 * l + 3] = pkfma(e.w, xk, base_v[4 * l + 3]);
            });
            const float4 f = *(const float4*)(Fp + k * 16);
            u_v[0] = pkfma(f.x, xk, u_v[0]);
            u_v[1] = pkfma(f.y, xk, u_v[1]);
            u_v[2] = pkfma(f.z, xk, u_v[2]);
            u_v[3] = pkfma(f.w, xk, u_v[3]);
        });
    });

    // ---- triangular relu solve, scatter form, j = 127..0 ----
    ufor<0, NW>([&](auto JJ) {
        constexpr int j  = NW - 1 - JJ.value;
        constexpr int tj = j & 3;     // owner slot of row j
        constexpr int mj = j >> 2;    // owner-local index
        const v2f cand = base_v[mj];
        const v2f w2 = {fmaxf(qbcast<tj>(cand.x), 0.f),
                        fmaxf(qbcast<tj>(cand.y), 0.f)};

        const float4 du = *(const float4*)(Up + j * 16);
        u_v[0] = pkfma(du.x, w2, u_v[0]);
        u_v[1] = pkfma(du.y, w2, u_v[1]);
        u_v[2] = pkfma(du.z, w2, u_v[2]);
        u_v[3] = pkfma(du.w, w2, u_v[3]);

        // scatter into rows i < j (worst slot t=0); tail masked by stored zeros
        constexpr int nL = (j + 15) >> 4;
        ufor<0, nL>([&](auto L) {
            constexpr int l = L.value;
            const float4 cc = *(const float4*)(Vp + j * 128 + 4 * l);
            base_v[4 * l + 0] = pkfma(cc.x, w2, base_v[4 * l + 0]);
            base_v[4 * l + 1] = pkfma(cc.y, w2, base_v[4 * l + 1]);
            base_v[4 * l + 2] = pkfma(cc.z, w2, base_v[4 * l + 2]);
            base_v[4 * l + 3] = pkfma(cc.w, w2, base_v[4 * l + 3]);
        });
    });

    // ---- write u: thread t owns u[4t..4t+4) for both elements ----
    const float4 o0 = make_float4(u_v[0].x, u_v[1].x, u_v[2].x, u_v[3].x);
    const float4 o1 = make_float4(u_v[0].y, u_v[1].y, u_v[2].y, u_v[3].y);
    *(float4*)(out + (size_t)b0 * NU + t * 4) = o0;
    *(float4*)(out + (size_t)b1 * NU + t * 4) = o1;
}

extern "C" void kernel_launch(void* const* d_in, const int* in_sizes, int n_in,
                              void* d_out, int out_size, void* d_ws, size_t ws_size,
                              hipStream_t stream) {
    const float* xi  = (const float*)d_in[0];
    const float* Cv  = (const float*)d_in[1];
    const float* Dvw = (const float*)d_in[2];
    const float* Dvy = (const float*)d_in[3];
    const float* Cu  = (const float*)d_in[4];
    const float* Duw = (const float*)d_in[5];
    const float* Duy = (const float*)d_in[6];
    float* out = (float*)d_out;
    float* ws  = (float*)d_ws;

    const int B = in_sizes[0] / NXI;  // 131072
    const int nhalf = B / 2;
    const int threads = nhalf * 4;    // 2 elements per thread

    prep_kernel<<<(WS_FLOATS + 255) / 256, 256, 0, stream>>>(Cv, Dvw, Dvy, Cu, Duw, Duy, ws);
    rinn_main<<<threads / 256, 256, 0, stream>>>(xi, ws, out, nhalf);
}

// Round 7
// 110.518 us; speedup vs baseline: 14.1806x; 5.7091x over previous
//
#include <hip/hip_runtime.h>

// RINN controller on MFMA (fp16 inputs, fp32 accum).
// B=131072, n_k=64, n_w=128, n_y=16, n_u=16. xi row = [y(16) | x_k(64)].
//
// Math: S[144 x B] = Emat[144x80] @ xi^T, rows 0..127 -> base (Dvy|Cv),
// rows 128..143 -> u-partial (Duy|Cu). Then blocked back-substitution over 8
// w-blocks of 16 (Dvw strictly upper): for K=7..0: serial 16-step diag solve
// (fp32 VALU, shfl broadcast), then MFMA rank-16 updates to lower blocks and
// to u (Duw). W B-fragment needs no cross-lane movement: k=4g+r == row 4g+r.
//
// MFMA layouts (gfx950): C/D: col=lane&15 (batch), row=4*(lane>>4)+reg [m89].
// A/B 16x16x32: 8 f16/lane, k=8*(lane>>4)+i. 16x16x16: 4 f16/lane,
// k=4*(lane>>4)+i. Prep kernel materializes every fragment per-lane in ws.
//
// R7 fixes vs R6 (compile): legacy builtin name is ..._16x16x16f16 (no
// underscore); build f16 fragments via scalar (_Float16) casts instead of
// cvt_pkrtz (returns __fp16 vector, type-clashes with _Float16 vectors).

#define NW 128
#define NK 64
#define NY 16
#define NU 16
#define NXI 80

// ws blob layout (bytes)
#define DENSE_OFF 0      // 9 tiles x (1024 + 1024 + 512) = 23040
#define SOLVE_OFF 23040  // 36 frags x 512 = 18432 (28 offdiag + 8 Duw)
#define DIAG_OFF  41472  // 8 blk x 16 step x 16 rows x f32 = 8192
#define BLOB_BYTES 49664
#define N_PREP_THREADS 12416  // 10368 u32 (f16 pairs) + 2048 f32

typedef _Float16 f16;
typedef __attribute__((ext_vector_type(4))) _Float16 f16x4;
typedef __attribute__((ext_vector_type(8))) _Float16 f16x8;
typedef __attribute__((ext_vector_type(4))) float f32x4;

template<int I> struct Ic { static constexpr int value = I; };
template<int I, int N, typename F>
__device__ __forceinline__ void ufor(F&& f) {
    if constexpr (I < N) { f(Ic<I>{}); ufor<I + 1, N>(static_cast<F&&>(f)); }
}

__device__ __forceinline__ float emat_val(int i, int k,
                                          const float* Cv, const float* Dvy,
                                          const float* Cu, const float* Duy) {
    if (i < NW) return (k < NY) ? Dvy[i * NY + k] : Cv[i * NK + (k - NY)];
    int r = i - NW;
    return (k < NY) ? Duy[r * NY + k] : Cu[r * NK + (k - NY)];
}

__global__ void prep(const float* __restrict__ Cv, const float* __restrict__ Dvw,
                     const float* __restrict__ Dvy, const float* __restrict__ Cu,
                     const float* __restrict__ Duw, const float* __restrict__ Duy,
                     unsigned int* __restrict__ ws) {
    int id = blockIdx.x * 256 + threadIdx.x;
    if (id >= N_PREP_THREADS) return;
    if (id < DIAG_OFF / 4) {  // f16-pair sections (dense + solve frags)
        int byte = id * 4;
        float v0, v1;
        if (byte < SOLVE_OFF) {
            int T = byte / 2560, rem = byte % 2560;
            int l, i0, kbase;
            if (rem < 2048) {            // 16x16x32 chunks 0,1
                int chunk = rem >> 10, cb = rem & 1023;
                l = cb >> 4; i0 = (cb & 15) >> 1;
                kbase = chunk * 32 + (l >> 4) * 8;
            } else {                     // 16x16x16 chunk2 (k=64..79)
                int cb = rem - 2048;
                l = cb >> 3; i0 = (cb & 7) >> 1;
                kbase = 64 + (l >> 4) * 4;
            }
            int row = T * 16 + (l & 15);
            v0 = emat_val(row, kbase + i0,     Cv, Dvy, Cu, Duy);
            v1 = emat_val(row, kbase + i0 + 1, Cv, Dvy, Cu, Duy);
        } else {                         // solve A-frags (16x16x16)
            int sb = byte - SOLVE_OFF;
            int f = sb >> 9, cb = sb & 511;
            int l = cb >> 3, i0 = (cb & 7) >> 1;
            int kk = (l >> 4) * 4 + i0;
            if (f < 28) {                // (J,K) pair, f = K*(K-1)/2 + J
                int K = 1; while ((K + 1) * K / 2 <= f) K++;
                int J = f - K * (K - 1) / 2;
                int row = J * 16 + (l & 15);
                v0 = Dvw[row * NW + K * 16 + kk];
                v1 = Dvw[row * NW + K * 16 + kk + 1];
            } else {                     // Duw frag for block K
                int K = f - 28;
                int r = l & 15;
                v0 = Duw[r * NW + K * 16 + kk];
                v1 = Duw[r * NW + K * 16 + kk + 1];
            }
        }
        union { _Float16 h[2]; unsigned u; } p;
        p.h[0] = (_Float16)v0; p.h[1] = (_Float16)v1;
        ws[id] = p.u;
    } else {                             // diag coeff blob, fp32
        int d = id - DIAG_OFF / 4;       // 0..2047
        int blk = d >> 8, rem = d & 255, j = rem >> 4, ii = rem & 15;
        // Dvw strict-upper: zero for ii >= j automatically (mask for free)
        ((float*)ws)[id] = Dvw[(blk * 16 + ii) * NW + blk * 16 + j];
    }
}

__global__ __launch_bounds__(512) void rinn_mfma(const float* __restrict__ xi,
                                                 const unsigned char* __restrict__ wsb,
                                                 float* __restrict__ out) {
    __shared__ __align__(16) unsigned char LDS[BLOB_BYTES];
    const int tid = threadIdx.x;
    {   // stage blob -> LDS (3104 uint4 = 49664 B)
        const uint4* src = (const uint4*)wsb;
        uint4* dst = (uint4*)LDS;
        ufor<0, 6>([&](auto IT) { dst[IT.value * 512 + tid] = src[IT.value * 512 + tid]; });
        if (tid < 32) dst[3072 + tid] = src[3072 + tid];
    }
    __syncthreads();

    const int lane = tid & 63;
    const int wv = tid >> 6;
    const int g = lane >> 4;       // row-group (M rows 4g..4g+3)
    const int c = lane & 15;       // batch column within tile
    const int batch0 = (blockIdx.x * 8 + wv) * 16;
    const float* __restrict__ xb = xi + (size_t)(batch0 + c) * NXI;

    f32x4 acc[9];
    ufor<0, 9>([&](auto T) { acc[T.value] = (f32x4){0.f, 0.f, 0.f, 0.f}; });

    // ---- dense: chunks 0,1 (16x16x32, k=0..63) ----
    ufor<0, 2>([&](auto KC) {
        constexpr int kc = KC.value;
        const float4 xa = *(const float4*)(xb + kc * 32 + g * 8);
        const float4 xc = *(const float4*)(xb + kc * 32 + g * 8 + 4);
        f16x8 Bf;
        Bf[0] = (f16)xa.x; Bf[1] = (f16)xa.y; Bf[2] = (f16)xa.z; Bf[3] = (f16)xa.w;
        Bf[4] = (f16)xc.x; Bf[5] = (f16)xc.y; Bf[6] = (f16)xc.z; Bf[7] = (f16)xc.w;
        ufor<0, 9>([&](auto T) {
            constexpr int t = T.value;
            const f16x8 Af = *(const f16x8*)&LDS[t * 2560 + kc * 1024 + lane * 16];
            acc[t] = __builtin_amdgcn_mfma_f32_16x16x32_f16(Af, Bf, acc[t], 0, 0, 0);
        });
    });
    // ---- dense: chunk2 (16x16x16, k=64..79) ----
    {
        const float4 xa = *(const float4*)(xb + 64 + g * 4);
        f16x4 Bf;
        Bf[0] = (f16)xa.x; Bf[1] = (f16)xa.y; Bf[2] = (f16)xa.z; Bf[3] = (f16)xa.w;
        ufor<0, 9>([&](auto T) {
            constexpr int t = T.value;
            const f16x4 Af = *(const f16x4*)&LDS[t * 2560 + 2048 + lane * 8];
            acc[t] = __builtin_amdgcn_mfma_f32_16x16x16f16(Af, Bf, acc[t], 0, 0, 0);
        });
    }

    const unsigned char* __restrict__ diagp = &LDS[DIAG_OFF + g * 16];

    // ---- blocked back-substitution, K = 7..0 ----
    ufor<0, 8>([&](auto QQ) {
        constexpr int K = 7 - QQ.value;
        // serial diag solve (fp32), local rows j = 15..0
        ufor<0, 16>([&](auto JJ) {
            constexpr int j = 15 - JJ.value;
            constexpr int gj = j >> 2, rj = j & 3;
            float s = __shfl(acc[K][rj], gj * 16 + c, 64);
            float w = fmaxf(s, 0.f);
            const f32x4 d = *(const f32x4*)(diagp + (K * 16 + j) * 64);
            acc[K][0] = fmaf(d[0], w, acc[K][0]);
            acc[K][1] = fmaf(d[1], w, acc[K][1]);
            acc[K][2] = fmaf(d[2], w, acc[K][2]);
            acc[K][3] = fmaf(d[3], w, acc[K][3]);
        });
        // W B-fragment: k=4g+r == this lane's rows; no cross-lane movement
        f16x4 Wf;
        Wf[0] = (f16)fmaxf(acc[K][0], 0.f);
        Wf[1] = (f16)fmaxf(acc[K][1], 0.f);
        Wf[2] = (f16)fmaxf(acc[K][2], 0.f);
        Wf[3] = (f16)fmaxf(acc[K][3], 0.f);
        // u += Duw[:,K] @ W_K
        {
            const f16x4 Af = *(const f16x4*)&LDS[SOLVE_OFF + (28 + K) * 512 + lane * 8];
            acc[8] = __builtin_amdgcn_mfma_f32_16x16x16f16(Af, Wf, acc[8], 0, 0, 0);
        }
        // S_J += Dvw[J,K] @ W_K for J < K
        ufor<0, K>([&](auto JB) {
            constexpr int J = JB.value;
            const f16x4 Af = *(const f16x4*)&LDS[SOLVE_OFF + (K * (K - 1) / 2 + J) * 512 + lane * 8];
            acc[J] = __builtin_amdgcn_mfma_f32_16x16x16f16(Af, Wf, acc[J], 0, 0, 0);
        });
    });

    // ---- write u tile: lane (g,c) holds u[4g..4g+3] of batch (batch0+c) ----
    float4 o = make_float4(acc[8][0], acc[8][1], acc[8][2], acc[8][3]);
    *(float4*)(out + (size_t)(batch0 + c) * NU + g * 4) = o;
}

extern "C" void kernel_launch(void* const* d_in, const int* in_sizes, int n_in,
                              void* d_out, int out_size, void* d_ws, size_t ws_size,
                              hipStream_t stream) {
    const float* xi  = (const float*)d_in[0];
    const float* Dvw = (const float*)d_in[2];
    const float* Cv  = (const float*)d_in[1];
    const float* Dvy = (const float*)d_in[3];
    const float* Cu  = (const float*)d_in[4];
    const float* Duw = (const float*)d_in[5];
    const float* Duy = (const float*)d_in[6];
    float* out = (float*)d_out;

    const int B = in_sizes[0] / NXI;  // 131072

    prep<<<(N_PREP_THREADS + 255) / 256, 256, 0, stream>>>(
        Cv, Dvw, Dvy, Cu, Duw, Duy, (unsigned int*)d_ws);
    rinn_mfma<<<B / 128, 512, 0, stream>>>(
        xi, (const unsigned char*)d_ws, out);
}